// Round 10
// baseline (196.071 us; speedup 1.0000x reference)
//
#include <hip/hip_runtime.h>
#include <hip/hip_cooperative_groups.h>

namespace cg = cooperative_groups;

typedef __attribute__((ext_vector_type(8))) short short8;   // 8 x bf16 (4 VGPR)
typedef __attribute__((ext_vector_type(4))) float f32x4;

#define Bsz 4
#define Cin 256
#define Cout 256
#define Hh 64
#define Ww 64
#define HW 4096
#define NG 16
#define EPSV 1e-5f

#define SPAN 12        // staged input rows per window
#define ROWB 4112      // staged row stride bytes: 16 pairs x 64 px x 4B + 16 pad

// ---- dcn dynamic LDS layout (bytes) ----
#define OFF_IN   0
#define SZ_IN    (SPAN * ROWB)         // 49344: bf16 pair-plane window
#define OFF_COL  49344                 // 9 taps x 2048 B fragment-major col
#define SZ_COL   (9 * 2048)            // 18432
#define OFF_CTL  67776                 // ymin/ymax
#define SMEM_BYTES 67792               // x2 blocks = 135584 <= 160 KiB/CU

static __device__ __forceinline__ unsigned f2bf(float f) {
    unsigned u = __float_as_uint(f);
    return (u + 0x7fffu + ((u >> 16) & 1u)) >> 16;   // RNE bf16
}

static __device__ __forceinline__ float2 ld8(const float* p) {
    float2 v;
    __builtin_memcpy(&v, p, 8);   // 8B load (global or LDS)
    return v;
}

#define BLO(u) __uint_as_float((u) << 16)          // bf16 in low half -> f32
#define BHI(u) __uint_as_float((u) & 0xffff0000u)  // bf16 in high half -> f32

// ---------------------------------------------------------------------------
// Shared phase macros (used by fused_kernel and the fallback dcn_kernel).
// They reference local identifiers (wv, lane, ymin, b, smem, col, acc, ...)
// present in both kernels.
// ---------------------------------------------------------------------------
#define STAGE(cc)                                                              \
    {                                                                          \
        _Pragma("unroll")                                                      \
        for (int i = 0; i < 6; i++) {                                          \
            const int g = wv * 6 + i;                                          \
            const int rr = g >> 2, seg = g & 3;                                \
            const int row = min(ymin + rr, 63);                                \
            const unsigned* src = inT +                                        \
                ((size_t)(b * 64 + row) * 128 + (cc) * 16) * 64 +              \
                seg * 256 + lane * 4;                                          \
            __builtin_amdgcn_global_load_lds(                                  \
                (const __attribute__((address_space(1))) void*)src,            \
                (__attribute__((address_space(3))) void*)(smem + OFF_IN +      \
                    rr * ROWB + seg * 1024),                                   \
                16, 0, 0);                                                     \
        }                                                                      \
    }

#define GATHER_PUB_L(kk)                                                   \
    {                                                                      \
        const unsigned ad = tad[kk];                                       \
        const float4 tw = tw4[kk];                                         \
        const char* bp = smem + OFF_IN + proff;                            \
        const float2 f0 = ld8((const float*)(bp + (ad & 0xffffu)));        \
        const float2 f1 = ld8((const float*)(bp + (ad >> 16)));            \
        const unsigned u00 = __float_as_uint(f0.x);                        \
        const unsigned u01 = __float_as_uint(f0.y);                        \
        const unsigned u10 = __float_as_uint(f1.x);                        \
        const unsigned u11 = __float_as_uint(f1.y);                        \
        const float v0 = tw.x * BLO(u00) + tw.y * BLO(u01) +               \
                         tw.z * BLO(u10) + tw.w * BLO(u11);                \
        const float v1 = tw.x * BHI(u00) + tw.y * BHI(u01) +               \
                         tw.z * BHI(u10) + tw.w * BHI(u11);                \
        *(unsigned*)&col[(kk) * 1024 + cslot] = f2bf(v0) | (f2bf(v1) << 16); \
    }

#define FRAGS_MFMA(ks, kk)                                                     \
    {                                                                          \
        const ushort* wp =                                                     \
            wtb + ((size_t)((ks) * 256 + wv * 32 + l15)) * 32 + quad * 8;      \
        const short8 a0 = *(const short8*)wp;                                  \
        const short8 a1 = *(const short8*)(wp + 16 * 32);                      \
        short8 bfr[2];                                                         \
        _Pragma("unroll")                                                      \
        for (int nt = 0; nt < 2; nt++)                                         \
            bfr[nt] = *(const short8*)&col[(kk) * 1024 + nt * 512 +            \
                                           quad * 128 + l15 * 8];              \
        _Pragma("unroll")                                                      \
        for (int nt = 0; nt < 2; nt++) {                                       \
            acc[0][nt] = __builtin_amdgcn_mfma_f32_16x16x32_bf16(              \
                a0, bfr[nt], acc[0][nt], 0, 0, 0);                             \
            acc[1][nt] = __builtin_amdgcn_mfma_f32_16x16x32_bf16(              \
                a1, bfr[nt], acc[1][nt], 0, 0, 0);                             \
        }                                                                      \
    }

// dcn main body: tap compute through MFMA loop. Leaves biased values in acc
// and gs/gq partial sums pushed to stats via atomics.  WRITE_OUT=1 also
// stores out directly (fallback kernel); WRITE_OUT=0 keeps acc for phase 3.
#define DCN_BODY(WRITE_OUT)                                                    \
    if (t < 2) s_ctl[t] = (t == 0) ? 64 : -1;                                  \
    __syncthreads();                                                           \
    const float* ob = offs + (size_t)b * 18 * HW + h * Ww + pp;                \
    const float* mb = mask + (size_t)b * 9 * HW + h * Ww + pp;                 \
    int ryc0[9], ryc1[9], rxb[9];                                              \
    float4 tw4[9];                                                             \
    int my_min = 64, my_max = -1;                                              \
    _Pragma("unroll")                                                          \
    for (int k = 0; k < 9; k++) {                                              \
        const float dy = ob[(2 * k) * HW];                                     \
        const float dx = ob[(2 * k + 1) * HW];                                 \
        const float m  = mb[k * HW];                                           \
        const float y = (float)h + (float)(k / 3 - 1) + dy;                    \
        const float x = (float)pp + (float)(k % 3 - 1) + dx;                   \
        const float y0f = floorf(y), x0f = floorf(x);                          \
        const float ly = y - y0f, lx = x - x0f;                                \
        const float hy = 1.f - ly, hx = 1.f - lx;                              \
        const int y0 = (int)y0f, x0 = (int)x0f;                                \
        const int yc0 = min(max(y0, 0), 63);                                   \
        const int yc1 = min(max(y0 + 1, 0), 63);                               \
        const int xb  = min(max(x0, 0), 62);                                   \
        float ax = 0.f, ay = 0.f;                                              \
        if (x0 == xb)      { ax = hx; ay = lx; }                               \
        else if (x0 < xb)  { ax = (x0 + 1 == 0) ? lx : 0.f; }                  \
        else               { ay = (x0 == 63) ? hx : 0.f; }                     \
        const float w0 = (y0 >= 0 && y0 < 64) ? m * hy : 0.f;                  \
        const float w1 = (y0 + 1 >= 0 && y0 + 1 < 64) ? m * ly : 0.f;          \
        ryc0[k] = yc0; ryc1[k] = yc1; rxb[k] = xb;                             \
        tw4[k] = make_float4(w0 * ax, w0 * ay, w1 * ax, w1 * ay);              \
        my_min = min(my_min, yc0);                                             \
        my_max = max(my_max, yc1);                                             \
    }                                                                          \
    _Pragma("unroll")                                                          \
    for (int off = 32; off; off >>= 1) {                                       \
        my_min = min(my_min, __shfl_xor(my_min, off));                         \
        my_max = max(my_max, __shfl_xor(my_max, off));                         \
    }                                                                          \
    if (lane == 0) {                                                           \
        atomicMin(&s_ctl[0], my_min);                                          \
        atomicMax(&s_ctl[1], my_max);                                          \
    }                                                                          \
    __syncthreads();                                                           \
    const int ymin = s_ctl[0];                                                 \
    const bool use_lds2 = (s_ctl[1] - ymin + 1) <= SPAN;                       \
    unsigned tad[9];                                                           \
    _Pragma("unroll")                                                          \
    for (int k = 0; k < 9; k++) {                                              \
        const unsigned r0 = (unsigned)((ryc0[k] - ymin) * ROWB + rxb[k] * 4);  \
        const unsigned r1 = (unsigned)((ryc1[k] - ymin) * ROWB + rxb[k] * 4);  \
        tad[k] = (r0 & 0xffffu) | (r1 << 16);                                  \
    }                                                                          \
    f32x4 acc[2][2];                                                           \
    _Pragma("unroll")                                                          \
    for (int i = 0; i < 2; i++)                                                \
        _Pragma("unroll")                                                      \
        for (int nt = 0; nt < 2; nt++) acc[i][nt] = (f32x4){0.f,0.f,0.f,0.f};  \
    const float* inb = in + (size_t)b * Cin * HW;                              \
    if (use_lds2) {                                                            \
        STAGE(0);                                                              \
        __syncthreads();                                                       \
        _Pragma("unroll 1")                                                    \
        for (int cc = 0; cc < 8; cc++) {                                       \
            _Pragma("unroll")                                                  \
            for (int kk = 0; kk < 9; kk++) GATHER_PUB_L(kk);                   \
            __syncthreads();                                                   \
            if (cc < 7) STAGE(cc + 1);                                         \
            _Pragma("unroll 3")                                                \
            for (int kk = 0; kk < 9; kk++) FRAGS_MFMA(kk * 8 + cc, kk);        \
            __syncthreads();                                                   \
        }                                                                      \
    } else {                                                                   \
        _Pragma("unroll 1")                                                    \
        for (int cc = 0; cc < 8; cc++) {                                       \
            _Pragma("unroll 1")                                                \
            for (int kk = 0; kk < 9; kk++) {                                   \
                const float dy = ob[(2 * kk) * HW];                            \
                const float dx = ob[(2 * kk + 1) * HW];                        \
                const float m  = mb[kk * HW];                                  \
                const float y = (float)h + (float)(kk / 3 - 1) + dy;           \
                const float x = (float)pp + (float)(kk % 3 - 1) + dx;          \
                const float y0f = floorf(y), x0f = floorf(x);                  \
                const float ly = y - y0f, lx = x - x0f;                        \
                const float hy = 1.f - ly, hx = 1.f - lx;                      \
                const int y0 = (int)y0f, x0 = (int)x0f;                        \
                const int yc0 = min(max(y0, 0), 63);                           \
                const int yc1 = min(max(y0 + 1, 0), 63);                       \
                const int xb  = min(max(x0, 0), 62);                           \
                float ax = 0.f, ay = 0.f;                                      \
                if (x0 == xb)      { ax = hx; ay = lx; }                       \
                else if (x0 < xb)  { ax = (x0 + 1 == 0) ? lx : 0.f; }          \
                else               { ay = (x0 == 63) ? hx : 0.f; }             \
                const float w0 = (y0 >= 0 && y0 < 64) ? m * hy : 0.f;          \
                const float w1 = (y0 + 1 >= 0 && y0 + 1 < 64) ? m * ly : 0.f;  \
                const int adx = yc0 * 64 + xb, ady = yc1 * 64 + xb;            \
                const float* cb = inb + (size_t)(cc*32 + wv*4 + hi*2) * HW;    \
                float vv[2];                                                   \
                _Pragma("unroll")                                              \
                for (int j = 0; j < 2; j++) {                                  \
                    const float* pl = cb + j * HW;                             \
                    const float2 g0 = ld8(pl + adx);                           \
                    const float2 g1 = ld8(pl + ady);                           \
                    vv[j] = (w0 * ax) * g0.x + (w0 * ay) * g0.y +              \
                            (w1 * ax) * g1.x + (w1 * ay) * g1.y;               \
                }                                                              \
                *(unsigned*)&col[kk * 1024 + cslot] =                          \
                    f2bf(vv[0]) | (f2bf(vv[1]) << 16);                         \
            }                                                                  \
            __syncthreads();                                                   \
            _Pragma("unroll 3")                                                \
            for (int kk = 0; kk < 9; kk++) FRAGS_MFMA(kk * 8 + cc, kk);        \
            __syncthreads();                                                   \
        }                                                                      \
    }                                                                          \
    float gs[2], gq[2];                                                        \
    _Pragma("unroll")                                                          \
    for (int i = 0; i < 2; i++) {                                              \
        float s = 0.f, qq = 0.f;                                               \
        const int ob2 = wv * 32 + i * 16 + quad * 4;                           \
        _Pragma("unroll")                                                      \
        for (int reg = 0; reg < 4; reg++) {                                    \
            const int o = ob2 + reg;                                           \
            const float bv = bias[o];                                          \
            float* op = out + ((size_t)(b * 256 + o)) * HW + h * Ww + wb + l15;\
            _Pragma("unroll")                                                  \
            for (int nt = 0; nt < 2; nt++) {                                   \
                const float v = acc[i][nt][reg] + bv;                          \
                acc[i][nt][reg] = v;                                           \
                if (WRITE_OUT) op[nt * 16] = v;                                \
                s += v;                                                        \
                qq += v * v;                                                   \
            }                                                                  \
        }                                                                      \
        gs[i] = s; gq[i] = qq;                                                 \
    }                                                                          \
    _Pragma("unroll")                                                          \
    for (int off = 32; off; off >>= 1) {                                       \
        gs[0] += __shfl_xor(gs[0], off);                                       \
        gq[0] += __shfl_xor(gq[0], off);                                       \
        gs[1] += __shfl_xor(gs[1], off);                                       \
        gq[1] += __shfl_xor(gq[1], off);                                       \
    }                                                                          \
    if (lane == 0) {                                                           \
        _Pragma("unroll")                                                      \
        for (int i = 0; i < 2; i++) {                                          \
            const int g = wv * 2 + i;                                          \
            atomicAdd(&stats[((size_t)b * NG + g) * 2],     gs[i]);            \
            atomicAdd(&stats[((size_t)b * NG + g) * 2 + 1], gq[i]);            \
        }                                                                      \
    }

// ---------------------------------------------------------------------------
// Fused cooperative kernel: prep | grid.sync | dcn | grid.sync | GN apply.
// Grid 512 x 512 thr = exactly 2 blocks/CU (135.6 KB LDS, VGPR<=128 via
// launch_bounds) -> co-residency for cooperative launch.
// ---------------------------------------------------------------------------
__launch_bounds__(512, 4)
__global__ void fused_kernel(const float* __restrict__ in,
                             const float* __restrict__ offs,
                             const float* __restrict__ mask,
                             const float* __restrict__ w,
                             const float* __restrict__ bias,
                             const float* __restrict__ gamma,
                             const float* __restrict__ beta,
                             float* __restrict__ out,
                             unsigned* __restrict__ inT,
                             ushort* __restrict__ wtb,
                             float* __restrict__ stats) {
    extern __shared__ char smem[];
    ushort* col  = (ushort*)(smem + OFF_COL);   // [9][1024] fragment-major
    int*    s_ctl = (int*)(smem + OFF_CTL);     // [0]=ymin [1]=ymax

    const int t  = threadIdx.x;
    const int bx = blockIdx.x;

    // ================= phase 1: prep (transpose + wt + stats zero) =========
    {
        // transpose slice: (b,y) = bx>>1 over 256 units, pr-half = bx&1
        const int pb = bx >> 7;                // batch 0..3
        const int py = (bx >> 1) & 63;         // row 0..63
        const int ph = bx & 1;                 // pr half 0..1
        const int x = t & 63, w8 = t >> 6;
        const float* src = in + (size_t)pb * 256 * HW + py * 64 + x;
        unsigned* dst = inT + ((size_t)(pb * 64 + py) * 128) * 64 + x;
#pragma unroll
        for (int it = 0; it < 8; it++) {
            const int pr = ph * 64 + w8 + it * 8;
            const float a0 = src[(size_t)(2 * pr) * HW];
            const float a1 = src[(size_t)(2 * pr + 1) * HW];
            dst[(size_t)pr * 64] = f2bf(a0) | (f2bf(a1) << 16);
        }
        // weight reorder slice: 1152 elements per block (512*1152 = 589824)
#pragma unroll
        for (int j = 0; j < 3; j++) {
            const int l = j * 512 + t;
            if (l < 1152) {
                const int i = bx * 1152 + l;
                const int cl = i & 31;
                const int o  = (i >> 5) & 255;
                const int ks = i >> 13;
                const int c  = ((ks & 7) << 5) | cl;
                const int kk = ks >> 3;
                wtb[i] = (ushort)f2bf(w[((size_t)o * Cin + c) * 9 + kk]);
            }
        }
        if (bx == 0 && t < 128) stats[t] = 0.f;
    }
    cg::this_grid().sync();

    // ================= phase 2: dcn (round-9 body, acc kept) ===============
    const int q  = bx & 7, r = bx >> 3;
    const int b  = q >> 1;
    const int h  = ((q & 1) << 5) | (r >> 1);
    const int wb = (r & 1) << 5;
    const int lane = t & 63;
    const int wv   = t >> 6;
    const int quad = lane >> 4;
    const int l15  = lane & 15;
    const int px   = lane & 31;
    const int hi   = lane >> 5;
    const int proff = (2 * wv + hi) * 256;
    const int pp   = wb + px;
    const int cslot = ((px >> 4) << 9) | ((wv >> 1) << 7) | ((px & 15) << 3) |
                      ((wv & 1) << 2) | (hi << 1);

    DCN_BODY(0)

    cg::this_grid().sync();

    // ================= phase 3: GN apply from registers, single store ======
    const float inv_n = 1.f / 65536.f;
#pragma unroll
    for (int i = 0; i < 2; i++) {
        const int g = wv * 2 + i;
        const float ssum = stats[((size_t)b * NG + g) * 2];
        const float sq   = stats[((size_t)b * NG + g) * 2 + 1];
        const float mu  = ssum * inv_n;
        const float var = sq * inv_n - mu * mu;
        const float rs  = rsqrtf(var + EPSV);
        const int ob2 = wv * 32 + i * 16 + quad * 4;
#pragma unroll
        for (int reg = 0; reg < 4; reg++) {
            const int o = ob2 + reg;
            const float ga = gamma[o] * rs;
            const float be = beta[o] - mu * ga;
            float* op = out + ((size_t)(b * 256 + o)) * HW + h * Ww + wb + l15;
#pragma unroll
            for (int nt = 0; nt < 2; nt++)
                op[nt * 16] = acc[i][nt][reg] * ga + be;
        }
    }
}

// ---------------------------------------------------------------------------
// Fallback path (3 kernels) — identical to round 9, kept in case cooperative
// launch is unavailable or fails.
// ---------------------------------------------------------------------------
__launch_bounds__(512)
__global__ void prep_kernel(const float* __restrict__ in,
                            const float* __restrict__ w,
                            unsigned* __restrict__ inT,
                            ushort* __restrict__ wtb,
                            float* __restrict__ stats) {
    const int t  = threadIdx.x;
    const int bx = blockIdx.x;
    if (bx < 256) {                    // ---- transpose ----
        const int b = bx >> 6, y = bx & 63;
        const int x = t & 63, w8 = t >> 6;
        const float* src = in + (size_t)b * 256 * HW + y * 64 + x;
        unsigned* dst = inT + ((size_t)(b * 64 + y) * 128) * 64 + x;
#pragma unroll
        for (int it = 0; it < 16; it++) {
            const int pr = w8 + it * 8;
            const float a0 = src[(size_t)(2 * pr) * HW];
            const float a1 = src[(size_t)(2 * pr + 1) * HW];
            dst[(size_t)pr * 64] = f2bf(a0) | (f2bf(a1) << 16);
        }
        return;
    }
    if (bx == 256 && t < 128) stats[t] = 0.f;
    const int i = (bx - 256) * 512 + t;
    if (i >= 72 * 256 * 32) return;
    const int cl = i & 31;
    const int o  = (i >> 5) & 255;
    const int ks = i >> 13;
    const int c  = ((ks & 7) << 5) | cl;
    const int kk = ks >> 3;
    wtb[i] = (ushort)f2bf(w[((size_t)o * Cin + c) * 9 + kk]);
}

__launch_bounds__(512, 4)
__global__ void dcn_kernel(const float* __restrict__ in,
                           const unsigned* __restrict__ inT,
                           const float* __restrict__ offs,
                           const float* __restrict__ mask,
                           const ushort* __restrict__ wtb,
                           const float* __restrict__ bias,
                           float* __restrict__ out,
                           float* __restrict__ stats) {
    extern __shared__ char smem[];
    ushort* col  = (ushort*)(smem + OFF_COL);
    int*    s_ctl = (int*)(smem + OFF_CTL);

    const int t  = threadIdx.x;
    const int bx = blockIdx.x;
    const int q  = bx & 7, r = bx >> 3;
    const int b  = q >> 1;
    const int h  = ((q & 1) << 5) | (r >> 1);
    const int wb = (r & 1) << 5;
    const int lane = t & 63;
    const int wv   = t >> 6;
    const int quad = lane >> 4;
    const int l15  = lane & 15;
    const int px   = lane & 31;
    const int hi   = lane >> 5;
    const int proff = (2 * wv + hi) * 256;
    const int pp   = wb + px;
    const int cslot = ((px >> 4) << 9) | ((wv >> 1) << 7) | ((px & 15) << 3) |
                      ((wv & 1) << 2) | (hi << 1);

    DCN_BODY(1)
}

#undef STAGE
#undef GATHER_PUB_L
#undef FRAGS_MFMA
#undef DCN_BODY

__global__ void gn_apply_kernel(float* __restrict__ x, const float* __restrict__ stats,
                                const float* __restrict__ gamma,
                                const float* __restrict__ beta) {
    const int i = blockIdx.x * 256 + threadIdx.x;
    const int plane = i >> 10;
    const int o = plane & 255;
    const int bg = plane >> 4;
    const float s = stats[bg * 2], q = stats[bg * 2 + 1];
    const float inv_n = 1.f / 65536.f;
    const float mu = s * inv_n;
    const float var = q * inv_n - mu * mu;
    const float rs = rsqrtf(var + EPSV);
    const float ga = gamma[o] * rs;
    const float be = beta[o] - mu * ga;
    float4 v = ((float4*)x)[i];
    v.x = v.x * ga + be;
    v.y = v.y * ga + be;
    v.z = v.z * ga + be;
    v.w = v.w * ga + be;
    ((float4*)x)[i] = v;
}

// ---------------------------------------------------------------------------
extern "C" void kernel_launch(void* const* d_in, const int* in_sizes, int n_in,
                              void* d_out, int out_size, void* d_ws, size_t ws_size,
                              hipStream_t stream) {
    const float* input  = (const float*)d_in[0];
    const float* offset = (const float*)d_in[1];
    const float* maskp  = (const float*)d_in[2];
    const float* weight = (const float*)d_in[3];
    const float* bias   = (const float*)d_in[4];
    const float* gamma  = (const float*)d_in[5];
    const float* beta   = (const float*)d_in[6];
    float* out = (float*)d_out;

    ushort* wtb  = (ushort*)d_ws;                           // 1.18 MB
    float* stats = (float*)((char*)d_ws + (size_t)Cout * Cin * 9 * sizeof(ushort));
    unsigned* inT = (unsigned*)((char*)d_ws + 1180160);     // 8 MB bf16 pair-plane

    static int mode = -1;
    if (mode < 0) {
        hipFuncSetAttribute((const void*)fused_kernel,
                            hipFuncAttributeMaxDynamicSharedMemorySize, SMEM_BYTES);
        hipFuncSetAttribute((const void*)dcn_kernel,
                            hipFuncAttributeMaxDynamicSharedMemorySize, SMEM_BYTES);
        int dev = 0, coop = 0;
        hipGetDevice(&dev);
        hipDeviceGetAttribute(&coop, hipDeviceAttributeCooperativeLaunch, dev);
        mode = coop ? 1 : 0;
    }

    if (mode == 1) {
        void* kargs[] = {(void*)&input, (void*)&offset, (void*)&maskp,
                         (void*)&weight, (void*)&bias, (void*)&gamma,
                         (void*)&beta, (void*)&out, (void*)&inT,
                         (void*)&wtb, (void*)&stats};
        hipError_t e = hipLaunchCooperativeKernel(
            (const void*)fused_kernel, dim3(512), dim3(512), kargs,
            SMEM_BYTES, stream);
        if (e == hipSuccess) return;
        mode = 0;   // permanent fallback
    }

    hipLaunchKernelGGL(prep_kernel, dim3(256 + 1152), dim3(512), 0, stream,
                       input, weight, inT, wtb, stats);
    hipLaunchKernelGGL(dcn_kernel, dim3(Bsz * Hh * 2), dim3(512), SMEM_BYTES, stream,
                       input, inT, offset, maskp, wtb, bias, out, stats);
    hipLaunchKernelGGL(gn_apply_kernel, dim3((Bsz * Cout * HW / 4) / 256), dim3(256), 0,
                       stream, out, stats, gamma, beta);
}